// Round 8
// baseline (659.957 us; speedup 1.0000x reference)
//
#include <hip/hip_runtime.h>
#include <stdint.h>

#define BTOK 2048
#define HDIM 512
#define VOC  32000
#define BM 128
#define BN 128
#define BKM 64                   // K per step (MX 32x32x64)
#define NKTM (HDIM / BKM)        // 8 K-steps
#define BLOBM (BM * BKM)         // 8192 B per (panel, kt) blob (fp8)
#define NVB (VOC / BN)           // 250
#define NRB (BTOK / BM)          // 16
#define NBLK (NVB * NRB)         // 4000 (fallback grid)
#define VBG 2
#define NVBG (NVB / VBG)         // 125
#define NSTRIP (NVBG * NRB)      // 2000
#define NSLOT (NVB * 2)          // 500 partial slots (vb x wave-n-half)

// ws layout:
//   [0, 256)        blocksums
//   [65536, ..)     fp8 blobs: s_in | t_in | s_w | t_w
//   [PART_OFF, ..)  partials[5][NSLOT][BTOK] f32
#define WS_BLOB_OFF 65536
#define INB_B ((size_t)BTOK * HDIM)
#define WB_B  ((size_t)VOC * HDIM)
#define BLOB_BYTES (2 * INB_B + 2 * WB_B)          // 34,865,152
#define PART_OFF (WS_BLOB_OFF + BLOB_BYTES)
#define PART_BYTES ((size_t)5 * NSLOT * BTOK * 4)  // 20,480,000
#define WS_NEED (PART_OFF + PART_BYTES)            // ~55.4 MB

typedef __attribute__((ext_vector_type(8)))  short bf16x8;
typedef __attribute__((ext_vector_type(4)))  float f32x4;
typedef __attribute__((ext_vector_type(16))) float f32x16;
typedef __attribute__((ext_vector_type(8)))  int   i32x8;

__device__ __forceinline__ unsigned short f2b(float f) {
    union { float f; uint32_t u; } x; x.f = f;
    uint32_t u = x.u;
    u += 0x7fffu + ((u >> 16) & 1u);   // RNE (fallback path)
    return (unsigned short)(u >> 16);
}

// ---------------------------------------------------------------------------
// Pass 1: f32 -> fp8 e4m3 blobs, 64B rows, full-address XOR swizzle:
//   e = (r*64 + cc) ^ ((r&7)<<4)
// Bits 4-6 of the XOR: bits 4-5 permute 16B granules within the row, bit 6
// flips the row LSB (bijective, R5 pattern). Read side applies the SAME XOR.
// Bank check: per b128 read, each bank-quad gets exactly 8 lanes (minimum)
// -> conflict-free.
// ---------------------------------------------------------------------------
__global__ __launch_bounds__(256) void convert_pack_mx(
    const float* __restrict__ s_in, const float* __restrict__ s_w,
    const float* __restrict__ t_in, const float* __restrict__ t_w,
    unsigned char* __restrict__ blob)
{
    unsigned char* sinb = blob;
    unsigned char* tinb = blob + INB_B;
    unsigned char* swb  = blob + 2 * INB_B;
    unsigned char* twb  = blob + 2 * INB_B + WB_B;
    const int total8 = (2 * BTOK + 2 * VOC) * (HDIM / 8);
    for (int f = blockIdx.x * 256 + threadIdx.x; f < total8; f += gridDim.x * 256) {
        const int row = f >> 6;            // 64 groups of 8 per source row
        const int c8i = f & 63;
        const float* src; unsigned char* dstb; int lrow;
        if (row < BTOK)                { src = s_in; dstb = sinb; lrow = row; }
        else if (row < BTOK + VOC)     { src = s_w;  dstb = swb;  lrow = row - BTOK; }
        else if (row < 2*BTOK + VOC)   { src = t_in; dstb = tinb; lrow = row - (BTOK + VOC); }
        else                           { src = t_w;  dstb = twb;  lrow = row - (2*BTOK + VOC); }
        const float* sp = src + (size_t)lrow * HDIM + c8i * 8;
        const float4 v0 = *reinterpret_cast<const float4*>(sp);
        const float4 v1 = *reinterpret_cast<const float4*>(sp + 4);
        const int p = lrow >> 7, r = lrow & 127;
        const int ccf = c8i * 8, kt = ccf >> 6, cc = ccf & 63;
        const int e = (r * BKM + cc) ^ ((r & 7) << 4);
        uint32_t w0 = 0, w1 = 0;
        w0 = __builtin_amdgcn_cvt_pk_fp8_f32(v0.x, v0.y, w0, false);
        w0 = __builtin_amdgcn_cvt_pk_fp8_f32(v0.z, v0.w, w0, true);
        w1 = __builtin_amdgcn_cvt_pk_fp8_f32(v1.x, v1.y, w1, false);
        w1 = __builtin_amdgcn_cvt_pk_fp8_f32(v1.z, v1.w, w1, true);
        uint2 pk; pk.x = w0; pk.y = w1;
        *reinterpret_cast<uint2*>(dstb + (size_t)(p * NKTM + kt) * BLOBM + e) = pk;
    }
}

__device__ __forceinline__ void gl_lds16(const unsigned char* g, unsigned char* l) {
    __builtin_amdgcn_global_load_lds(
        (__attribute__((address_space(1))) const void*)g,
        (__attribute__((address_space(3))) void*)l, 16, 0, 0);
}

// Read one 32B MFMA operand (v8i32) from a swizzled 128x64 panel.
__device__ __forceinline__ i32x8 ld32(const unsigned char* base, int row, int khalf) {
    const int swz = (row & 7) << 4;
    const int a0 = (row * BKM + khalf * 32) ^ swz;
    const int a1 = (row * BKM + khalf * 32 + 16) ^ swz;
    const int4 lo = *reinterpret_cast<const int4*>(base + a0);
    const int4 hi = *reinterpret_cast<const int4*>(base + a1);
    i32x8 v;
    v[0] = lo.x; v[1] = lo.y; v[2] = lo.z; v[3] = lo.w;
    v[4] = hi.x; v[5] = hi.y; v[6] = hi.z; v[7] = hi.w;
    return v;
}

// 8 gl_lds per thread per step (4 panels x 8KB, 256 thr x 16B x 2).
#define STAGE_MX(KT, B)                                                       \
    {                                                                         \
        const size_t kb = (size_t)(KT) * BLOBM;                               \
        _Pragma("unroll")                                                     \
        for (int i = 0; i < 2; ++i) {                                         \
            const int off = i * 4096 + tid * 16;                              \
            gl_lds16(g0 + kb + off, &smem[B][0][off]);                        \
            gl_lds16(g1 + kb + off, &smem[B][1][off]);                        \
            gl_lds16(g2 + kb + off, &smem[B][2][off]);                        \
            gl_lds16(g3 + kb + off, &smem[B][3][off]);                        \
        }                                                                     \
    }

// 8 MFMA (32x32x64 MX, scale=1.0: E8M0 127) + 16 ds_read_b128 per wave.
#define COMPUTE_MX(B)                                                         \
    {                                                                         \
        i32x8 fa[2], fb[2];                                                   \
        _Pragma("unroll")                                                     \
        for (int mi = 0; mi < 2; ++mi)                                        \
            fa[mi] = ld32(smem[B][0], wm + mi * 32 + lrow, khalf);            \
        _Pragma("unroll")                                                     \
        for (int ni = 0; ni < 2; ++ni)                                        \
            fb[ni] = ld32(smem[B][1], wn + ni * 32 + lrow, khalf);            \
        _Pragma("unroll")                                                     \
        for (int mi = 0; mi < 2; ++mi)                                        \
            _Pragma("unroll")                                                 \
            for (int ni = 0; ni < 2; ++ni)                                    \
                acc_s[mi][ni] = __builtin_amdgcn_mfma_scale_f32_32x32x64_f8f6f4( \
                    fa[mi], fb[ni], acc_s[mi][ni], 0, 0, 0, 127, 0, 127);     \
        _Pragma("unroll")                                                     \
        for (int mi = 0; mi < 2; ++mi)                                        \
            fa[mi] = ld32(smem[B][2], wm + mi * 32 + lrow, khalf);            \
        _Pragma("unroll")                                                     \
        for (int ni = 0; ni < 2; ++ni)                                        \
            fb[ni] = ld32(smem[B][3], wn + ni * 32 + lrow, khalf);            \
        _Pragma("unroll")                                                     \
        for (int mi = 0; mi < 2; ++mi)                                        \
            _Pragma("unroll")                                                 \
            for (int ni = 0; ni < 2; ++ni)                                    \
                acc_t[mi][ni] = __builtin_amdgcn_mfma_scale_f32_32x32x64_f8f6f4( \
                    fa[mi], fb[ni], acc_t[mi][ni], 0, 0, 0, 127, 0, 127);     \
    }

// Counted vmcnt (T4): next step's 8 loads stay in flight across the barrier.
#define STEP_MX(KT, B)                                                        \
    {                                                                         \
        if ((KT) + 1 < NKTM) {                                                \
            STAGE_MX((KT) + 1, (B) ^ 1);                                      \
            asm volatile("s_waitcnt vmcnt(8)" ::: "memory");                  \
        } else {                                                              \
            asm volatile("s_waitcnt vmcnt(0)" ::: "memory");                  \
        }                                                                     \
        __builtin_amdgcn_sched_barrier(0);                                    \
        __builtin_amdgcn_s_barrier();                                         \
        COMPUTE_MX(B);                                                        \
        __builtin_amdgcn_s_barrier();                                         \
    }

// ---------------------------------------------------------------------------
// Strip GEMM (MX fp8 32x32x64): (row-block, 2 vocab-blocks) per block;
// per-GEMM partials written non-atomically to 500 slots (frees 80 VGPRs).
// ---------------------------------------------------------------------------
__global__ __launch_bounds__(256, 2) void fused_gemm_mx(
    const unsigned char* __restrict__ blob,
    const int* __restrict__ labels, float* __restrict__ partials)
{
    __shared__ __align__(16) unsigned char smem[2][4][BLOBM];   // 64 KB
    __shared__ int lbl[BM];
    const unsigned char* sinb = blob;
    const unsigned char* tinb = blob + INB_B;
    const unsigned char* swb  = blob + 2 * INB_B;
    const unsigned char* twb  = blob + 2 * INB_B + WB_B;

    const int tid = threadIdx.x;
    const int orig = blockIdx.x;
    const int swzb = (orig & 7) * (NSTRIP / 8) + (orig >> 3);   // XCD-bijective
    const int vbg = swzb >> 4, rb = swzb & 15;
    const int row0 = rb * BM;
    if (tid < BM) lbl[tid] = labels[row0 + tid];

    const int lane = tid & 63, wave = tid >> 6;
    const int wm = (wave >> 1) * 64, wn = (wave & 1) * 64;
    const int lrow = lane & 31, khalf = lane >> 5;

    const unsigned char* g0 = sinb + (size_t)(rb * NKTM) * BLOBM;
    const unsigned char* g2 = tinb + (size_t)(rb * NKTM) * BLOBM;

    for (int g = 0; g < VBG; ++g) {
        const int vb = vbg * VBG + g;
        const int n0 = vb * BN;
        const unsigned char* g1 = swb + (size_t)(vb * NKTM) * BLOBM;
        const unsigned char* g3 = twb + (size_t)(vb * NKTM) * BLOBM;

        f32x16 acc_s[2][2] = {};
        f32x16 acc_t[2][2] = {};

        STAGE_MX(0, 0);
#pragma unroll
        for (int kt = 0; kt < NKTM; kt += 2) {
            STEP_MX(kt, 0);
            STEP_MX(kt + 1, 1);
        }

        // C/D (32x32, m74/m101): col = lane&31, row = (reg&3)+8*(reg>>2)+4*(lane>>5)
        const int slot = vb * 2 + (wave & 1);
#pragma unroll
        for (int mi = 0; mi < 2; ++mi) {
#pragma unroll
            for (int rg = 0; rg < 16; ++rg) {
                const int rloc = wm + mi * 32 + (rg & 3) + 8 * (rg >> 2) + 4 * khalf;
                const int lab = lbl[rloc];
                const float s0 = acc_s[mi][0][rg], s1 = acc_s[mi][1][rg];
                const float t0 = acc_t[mi][0][rg], t1 = acc_t[mi][1][rg];
                float es = __expf(s0) + __expf(s1);
                float dt = s0 * t0 + s1 * t1;
                float ss = s0 * s0 + s1 * s1;
                float tt = t0 * t0 + t1 * t1;
                float sl = 0.f;
                if (n0 + wn + lrow == lab)      sl += s0;
                if (n0 + wn + 32 + lrow == lab) sl += s1;
#pragma unroll
                for (int m = 1; m < 32; m <<= 1) {
                    es += __shfl_xor(es, m, 64);
                    dt += __shfl_xor(dt, m, 64);
                    ss += __shfl_xor(ss, m, 64);
                    tt += __shfl_xor(tt, m, 64);
                    sl += __shfl_xor(sl, m, 64);
                }
                if (lrow == 0) {
                    const int row = row0 + rloc;
                    partials[(size_t)(0 * NSLOT + slot) * BTOK + row] = es;
                    partials[(size_t)(1 * NSLOT + slot) * BTOK + row] = dt;
                    partials[(size_t)(2 * NSLOT + slot) * BTOK + row] = ss;
                    partials[(size_t)(3 * NSLOT + slot) * BTOK + row] = tt;
                    partials[(size_t)(4 * NSLOT + slot) * BTOK + row] = sl;
                }
            }
        }
    }
}

// ---------------------------------------------------------------------------
// finalize stage 1: 32 blocks x 64 rows; reduce 500 slots (coalesced).
// ---------------------------------------------------------------------------
__global__ __launch_bounds__(256) void finalize_s1(
    const float* __restrict__ partials, const int* __restrict__ labels,
    float* __restrict__ blocksums)
{
    __shared__ float fsum[4][64][5];
    const int t = threadIdx.x, b = blockIdx.x;
    const int rl = t & 63, w = t >> 6;
    const int row = b * 64 + rl;
    float a0 = 0.f, a1 = 0.f, a2 = 0.f, a3 = 0.f, a4 = 0.f;
    for (int slot = w; slot < NSLOT; slot += 4) {
        const size_t base = (size_t)slot * BTOK + row;
        a0 += partials[(size_t)0 * NSLOT * BTOK + base];
        a1 += partials[(size_t)1 * NSLOT * BTOK + base];
        a2 += partials[(size_t)2 * NSLOT * BTOK + base];
        a3 += partials[(size_t)3 * NSLOT * BTOK + base];
        a4 += partials[(size_t)4 * NSLOT * BTOK + base];
    }
    fsum[w][rl][0] = a0; fsum[w][rl][1] = a1; fsum[w][rl][2] = a2;
    fsum[w][rl][3] = a3; fsum[w][rl][4] = a4;
    __syncthreads();
    if (t < 64) {
        const float es = fsum[0][t][0] + fsum[1][t][0] + fsum[2][t][0] + fsum[3][t][0];
        const float dt = fsum[0][t][1] + fsum[1][t][1] + fsum[2][t][1] + fsum[3][t][1];
        const float ss = fsum[0][t][2] + fsum[1][t][2] + fsum[2][t][2] + fsum[3][t][2];
        const float tt = fsum[0][t][3] + fsum[1][t][3] + fsum[2][t][3] + fsum[3][t][3];
        const float sl = fsum[0][t][4] + fsum[1][t][4] + fsum[2][t][4] + fsum[3][t][4];
        float hard = 0.f, soft;
        if (labels[row] != -100) hard = logf(es) - sl;
        const float ns = fmaxf(sqrtf(ss), 1e-12f);
        const float nt = fmaxf(sqrtf(tt), 1e-12f);
        soft = 1.f - dt / (ns * nt);
#pragma unroll
        for (int m = 1; m < 64; m <<= 1) {
            hard += __shfl_xor(hard, m, 64);
            soft += __shfl_xor(soft, m, 64);
        }
        if (t == 0) {
            blocksums[b * 2 + 0] = hard;
            blocksums[b * 2 + 1] = soft;
        }
    }
}

__global__ void finalize_s2(const float* __restrict__ blocksums,
                            float* __restrict__ out)
{
    const int t = threadIdx.x;   // 64
    float hard = (t < 32) ? blocksums[t * 2 + 0] : 0.f;
    float soft = (t < 32) ? blocksums[t * 2 + 1] : 0.f;
#pragma unroll
    for (int m = 1; m < 64; m <<= 1) {
        hard += __shfl_xor(hard, m, 64);
        soft += __shfl_xor(soft, m, 64);
    }
    if (t == 0)
        out[0] = 0.5f * (hard / (float)BTOK) + 0.25f * (soft / (float)BTOK);
}

// ---------------------------------------------------------------------------
// Fallback (ws too small): R2's validated bf16 fused-conversion kernel.
// ---------------------------------------------------------------------------
#define BKF 32
#define NKTF (HDIM / BKF)
#define TILE_EF (BM * BKF)

__device__ __forceinline__ int swz_e32(int r, int c) {
    return (r * BKF + c) ^ ((r & 7) << 3);
}

__global__ __launch_bounds__(256, 2) void fused_fwd_fb(
    const float* __restrict__ s_in, const float* __restrict__ s_w,
    const float* __restrict__ t_in, const float* __restrict__ t_w,
    const int* __restrict__ labels, float* __restrict__ rowacc)
{
    __shared__ unsigned short smem[2][4][TILE_EF];
    __shared__ int lbl[BM];
    const int tid = threadIdx.x;
    const int orig = blockIdx.x;
    const int swz  = (orig & 7) * (NBLK / 8) + (orig >> 3);
    const int vb = swz >> 4, rb = swz & 15;
    const int n0 = vb * BN, row0 = rb * BM;
    if (tid < BM) lbl[tid] = labels[row0 + tid];
    const int rr = tid >> 3, c8 = tid & 7;
    const float* srcp[4];
    srcp[0] = s_in + (size_t)(row0 + rr) * HDIM + c8 * 4;
    srcp[1] = s_w  + (size_t)(n0   + rr) * HDIM + c8 * 4;
    srcp[2] = t_in + (size_t)(row0 + rr) * HDIM + c8 * 4;
    srcp[3] = t_w  + (size_t)(n0   + rr) * HDIM + c8 * 4;
    f32x4 acc_s[4][4] = {}, acc_t[4][4] = {};
    const int lane = tid & 63, wave = tid >> 6;
    const int wm = (wave >> 1) * 64, wn = (wave & 1) * 64;
    const int lr = lane & 15, lg = lane >> 4;
    const int ec = lg * 8;
    float4 rg[4][4];

#define LOADS_FB(KT)                                                          \
    { const int k0 = (KT) * BKF;                                              \
      _Pragma("unroll") for (int t = 0; t < 4; ++t)                           \
      _Pragma("unroll") for (int it = 0; it < 4; ++it)                        \
          rg[t][it] = *reinterpret_cast<const float4*>(srcp[t] + (size_t)it * 32 * HDIM + k0); }
#define CVT_WRITE_FB(B)                                                       \
    { _Pragma("unroll") for (int t = 0; t < 4; ++t)                           \
      _Pragma("unroll") for (int it = 0; it < 4; ++it) {                      \
          const int r = rr + it * 32;                                         \
          ushort4 h;                                                          \
          h.x = f2b(rg[t][it].x); h.y = f2b(rg[t][it].y);                     \
          h.z = f2b(rg[t][it].z); h.w = f2b(rg[t][it].w);                     \
          *reinterpret_cast<ushort4*>(&smem[B][t][swz_e32(r, c8 * 4)]) = h; } }
#define COMPUTE_FB(B)                                                         \
    { const unsigned short* As = smem[B][0]; const unsigned short* Bs = smem[B][1]; \
      const unsigned short* At = smem[B][2]; const unsigned short* Bt = smem[B][3]; \
      bf16x8 af[4], bfr[4];                                                   \
      _Pragma("unroll") for (int mi = 0; mi < 4; ++mi)                        \
          af[mi] = *reinterpret_cast<const bf16x8*>(As + swz_e32(wm + mi * 16 + lr, ec)); \
      _Pragma("unroll") for (int ni = 0; ni < 4; ++ni)                        \
          bfr[ni] = *reinterpret_cast<const bf16x8*>(Bs + swz_e32(wn + ni * 16 + lr, ec)); \
      _Pragma("unroll") for (int mi = 0; mi < 4; ++mi)                        \
      _Pragma("unroll") for (int ni = 0; ni < 4; ++ni)                        \
          acc_s[mi][ni] = __builtin_amdgcn_mfma_f32_16x16x32_bf16(af[mi], bfr[ni], acc_s[mi][ni], 0, 0, 0); \
      _Pragma("unroll") for (int mi = 0; mi < 4; ++mi)                        \
          af[mi] = *reinterpret_cast<const bf16x8*>(At + swz_e32(wm + mi * 16 + lr, ec)); \
      _Pragma("unroll") for (int ni = 0; ni < 4; ++ni)                        \
          bfr[ni] = *reinterpret_cast<const bf16x8*>(Bt + swz_e32(wn + ni * 16 + lr, ec)); \
      _Pragma("unroll") for (int mi = 0; mi < 4; ++mi)                        \
      _Pragma("unroll") for (int ni = 0; ni < 4; ++ni)                        \
          acc_t[mi][ni] = __builtin_amdgcn_mfma_f32_16x16x32_bf16(af[mi], bfr[ni], acc_t[mi][ni], 0, 0, 0); }

    LOADS_FB(0); CVT_WRITE_FB(0); __syncthreads();
    int cur = 0;
#pragma unroll 2
    for (int kt = 0; kt < NKTF; ++kt) {
        if (kt + 1 < NKTF) LOADS_FB(kt + 1);
        COMPUTE_FB(cur);
        if (kt + 1 < NKTF) CVT_WRITE_FB(cur ^ 1);
        __syncthreads();
        cur ^= 1;
    }
#undef LOADS_FB
#undef CVT_WRITE_FB
#undef COMPUTE_FB
#pragma unroll
    for (int mi = 0; mi < 4; ++mi) {
#pragma unroll
        for (int rg_ = 0; rg_ < 4; ++rg_) {
            const int rloc = wm + mi * 16 + lg * 4 + rg_;
            const int lab = lbl[rloc];
            float es = 0.f, dt = 0.f, ss = 0.f, tt = 0.f, sl = 0.f;
#pragma unroll
            for (int ni = 0; ni < 4; ++ni) {
                const float s = acc_s[mi][ni][rg_];
                const float t = acc_t[mi][ni][rg_];
                es += __expf(s); dt += s * t; ss += s * s; tt += t * t;
                if (n0 + wn + ni * 16 + lr == lab) sl += s;
            }
#pragma unroll
            for (int m = 1; m < 16; m <<= 1) {
                es += __shfl_xor(es, m, 64); dt += __shfl_xor(dt, m, 64);
                ss += __shfl_xor(ss, m, 64); tt += __shfl_xor(tt, m, 64);
                sl += __shfl_xor(sl, m, 64);
            }
            if (lr == 0) {
                float* ra = rowacc + (size_t)(row0 + rloc) * 5;
                atomicAdd(ra + 0, es); atomicAdd(ra + 1, dt); atomicAdd(ra + 2, ss);
                atomicAdd(ra + 3, tt); atomicAdd(ra + 4, sl);
            }
        }
    }
}

__global__ __launch_bounds__(256) void finalize(const float* __restrict__ rowacc,
                                                const int* __restrict__ labels,
                                                float* __restrict__ out)
{
    const int tid = threadIdx.x;
    float hard = 0.f, soft = 0.f;
    for (int r = tid; r < BTOK; r += 256) {
        const float* ra = rowacc + (size_t)r * 5;
        const float es = ra[0], dt = ra[1], ss = ra[2], tt = ra[3], sl = ra[4];
        if (labels[r] != -100) hard += logf(es) - sl;
        const float ns = fmaxf(sqrtf(ss), 1e-12f);
        const float nt = fmaxf(sqrtf(tt), 1e-12f);
        soft += 1.f - dt / (ns * nt);
    }
#pragma unroll
    for (int m = 1; m < 64; m <<= 1) {
        hard += __shfl_xor(hard, m, 64);
        soft += __shfl_xor(soft, m, 64);
    }
    __shared__ float sh[2][4];
    const int w = tid >> 6;
    if ((tid & 63) == 0) { sh[0][w] = hard; sh[1][w] = soft; }
    __syncthreads();
    if (tid == 0) {
        const float h = sh[0][0] + sh[0][1] + sh[0][2] + sh[0][3];
        const float s = sh[1][0] + sh[1][1] + sh[1][2] + sh[1][3];
        out[0] = 0.5f * (h / (float)BTOK) + 0.5f * (0.5f * s / (float)BTOK);
    }
}

extern "C" void kernel_launch(void* const* d_in, const int* in_sizes, int n_in,
                              void* d_out, int out_size, void* d_ws, size_t ws_size,
                              hipStream_t stream)
{
    const float* s_in   = (const float*)d_in[0];
    const float* s_w    = (const float*)d_in[1];
    const float* t_in   = (const float*)d_in[2];
    const float* t_w    = (const float*)d_in[3];
    const int*   labels = (const int*)d_in[4];

    if (ws_size >= WS_NEED) {
        unsigned char* blob = (unsigned char*)d_ws + WS_BLOB_OFF;
        float* partials  = (float*)((char*)d_ws + PART_OFF);
        float* blocksums = (float*)d_ws;
        convert_pack_mx<<<2048, 256, 0, stream>>>(s_in, s_w, t_in, t_w, blob);
        fused_gemm_mx<<<NSTRIP, 256, 0, stream>>>(blob, labels, partials);
        finalize_s1<<<BTOK / 64, 256, 0, stream>>>(partials, labels, blocksums);
        finalize_s2<<<1, 64, 0, stream>>>(blocksums, (float*)d_out);
    } else {
        float* rowacc = (float*)d_ws;
        hipMemsetAsync(rowacc, 0, (size_t)BTOK * 5 * sizeof(float), stream);
        fused_fwd_fb<<<NBLK, 256, 0, stream>>>(s_in, s_w, t_in, t_w, labels, rowacc);
        finalize<<<1, 256, 0, stream>>>(rowacc, labels, (float*)d_out);
    }
}

// Round 9
// 330.727 us; speedup vs baseline: 1.9955x; 1.9955x over previous
//
#include <hip/hip_runtime.h>
#include <stdint.h>

#define BTOK 2048
#define HDIM 512
#define VOC  32000
#define BM 128
#define BN 128
#define BKM 64                   // K per step (MX 32x32x64)
#define NKTM (HDIM / BKM)        // 8 K-steps
#define BLOBM (BM * BKM)         // 8192 B per (panel, kt) blob (fp8)
#define NVB (VOC / BN)           // 250
#define NRB (BTOK / BM)          // 16
#define NBLK (NVB * NRB)         // 4000 (fallback grid)
#define VBG 2
#define NVBG (NVB / VBG)         // 125
#define NSTRIP (NVBG * NRB)      // 2000
#define NSLOT (NVB * 2)          // 500 partial slots (vb x wave-n-half)

// ws layout:
//   [0, 256)        blocksums
//   [65536, ..)     fp8 blobs: s_in | t_in | s_w | t_w
//   [PART_OFF, ..)  partials[5][NSLOT][BTOK] f32
#define WS_BLOB_OFF 65536
#define INB_B ((size_t)BTOK * HDIM)
#define WB_B  ((size_t)VOC * HDIM)
#define BLOB_BYTES (2 * INB_B + 2 * WB_B)          // 34,865,152
#define PART_OFF (WS_BLOB_OFF + BLOB_BYTES)
#define PART_BYTES ((size_t)5 * NSLOT * BTOK * 4)  // 20,480,000
#define WS_NEED (PART_OFF + PART_BYTES)            // ~55.4 MB

typedef __attribute__((ext_vector_type(8)))  short bf16x8;
typedef __attribute__((ext_vector_type(4)))  float f32x4;
typedef __attribute__((ext_vector_type(16))) float f32x16;
typedef __attribute__((ext_vector_type(8)))  int   i32x8;

__device__ __forceinline__ unsigned short f2b(float f) {
    union { float f; uint32_t u; } x; x.f = f;
    uint32_t u = x.u;
    u += 0x7fffu + ((u >> 16) & 1u);   // RNE (fallback path)
    return (unsigned short)(u >> 16);
}

// ---------------------------------------------------------------------------
// Pass 1: f32 -> fp8 e4m3 blobs, 64B rows, full-address XOR swizzle:
//   e = (r*64 + cc) ^ ((r&7)<<4)
// (bits 4-5 permute 16B granules; bit 6 flips row LSB - bijective, R5 rule.)
// Read side applies the SAME involution.
// ---------------------------------------------------------------------------
__global__ __launch_bounds__(256) void convert_pack_mx(
    const float* __restrict__ s_in, const float* __restrict__ s_w,
    const float* __restrict__ t_in, const float* __restrict__ t_w,
    unsigned char* __restrict__ blob)
{
    unsigned char* sinb = blob;
    unsigned char* tinb = blob + INB_B;
    unsigned char* swb  = blob + 2 * INB_B;
    unsigned char* twb  = blob + 2 * INB_B + WB_B;
    const int total8 = (2 * BTOK + 2 * VOC) * (HDIM / 8);
    for (int f = blockIdx.x * 256 + threadIdx.x; f < total8; f += gridDim.x * 256) {
        const int row = f >> 6;
        const int c8i = f & 63;
        const float* src; unsigned char* dstb; int lrow;
        if (row < BTOK)                { src = s_in; dstb = sinb; lrow = row; }
        else if (row < BTOK + VOC)     { src = s_w;  dstb = swb;  lrow = row - BTOK; }
        else if (row < 2*BTOK + VOC)   { src = t_in; dstb = tinb; lrow = row - (BTOK + VOC); }
        else                           { src = t_w;  dstb = twb;  lrow = row - (2*BTOK + VOC); }
        const float* sp = src + (size_t)lrow * HDIM + c8i * 8;
        const float4 v0 = *reinterpret_cast<const float4*>(sp);
        const float4 v1 = *reinterpret_cast<const float4*>(sp + 4);
        const int p = lrow >> 7, r = lrow & 127;
        const int ccf = c8i * 8, kt = ccf >> 6, cc = ccf & 63;
        const int e = (r * BKM + cc) ^ ((r & 7) << 4);
        uint32_t w0 = 0, w1 = 0;
        w0 = __builtin_amdgcn_cvt_pk_fp8_f32(v0.x, v0.y, w0, false);
        w0 = __builtin_amdgcn_cvt_pk_fp8_f32(v0.z, v0.w, w0, true);
        w1 = __builtin_amdgcn_cvt_pk_fp8_f32(v1.x, v1.y, w1, false);
        w1 = __builtin_amdgcn_cvt_pk_fp8_f32(v1.z, v1.w, w1, true);
        uint2 pk; pk.x = w0; pk.y = w1;
        *reinterpret_cast<uint2*>(dstb + (size_t)(p * NKTM + kt) * BLOBM + e) = pk;
    }
}

__device__ __forceinline__ void gl_lds16(const unsigned char* g, unsigned char* l) {
    __builtin_amdgcn_global_load_lds(
        (__attribute__((address_space(1))) const void*)g,
        (__attribute__((address_space(3))) void*)l, 16, 0, 0);
}

// Read one 32B MFMA operand from a swizzled 128x64 panel.
__device__ __forceinline__ i32x8 ld32(const unsigned char* base, int row, int khalf) {
    const int swz = (row & 7) << 4;
    const int a0 = (row * BKM + khalf * 32) ^ swz;
    const int a1 = (row * BKM + khalf * 32 + 16) ^ swz;
    const int4 lo = *reinterpret_cast<const int4*>(base + a0);
    const int4 hi = *reinterpret_cast<const int4*>(base + a1);
    i32x8 v;
    v[0] = lo.x; v[1] = lo.y; v[2] = lo.z; v[3] = lo.w;
    v[4] = hi.x; v[5] = hi.y; v[6] = hi.z; v[7] = hi.w;
    return v;
}

// 512 threads x 16B = one full 8KB panel per gl_lds16 round: 4 loads/thread.
#define STAGE_MX(KT, B)                                                       \
    {                                                                         \
        const size_t kb = (size_t)(KT) * BLOBM;                               \
        const int off = tid * 16;                                             \
        gl_lds16(g0 + kb + off, &smem[B][0][off]);                            \
        gl_lds16(g1 + kb + off, &smem[B][1][off]);                            \
        gl_lds16(g2 + kb + off, &smem[B][2][off]);                            \
        gl_lds16(g3 + kb + off, &smem[B][3][off]);                            \
    }

// Per wave: 1 A-frag + 2 B-frags, 2+2 mfma_scale (scale=1.0: E8M0 127).
// Frag regs reused between student and teacher (register economy, no spill).
#define COMPUTE_MX(B)                                                         \
    {                                                                         \
        i32x8 fa, fb0, fb1;                                                   \
        fa  = ld32(smem[B][0], wm + lrow, khalf);                             \
        fb0 = ld32(smem[B][1], wn + lrow, khalf);                             \
        fb1 = ld32(smem[B][1], wn + 32 + lrow, khalf);                        \
        acc_s0 = __builtin_amdgcn_mfma_scale_f32_32x32x64_f8f6f4(             \
            fa, fb0, acc_s0, 0, 0, 0, 127, 0, 127);                           \
        acc_s1 = __builtin_amdgcn_mfma_scale_f32_32x32x64_f8f6f4(             \
            fa, fb1, acc_s1, 0, 0, 0, 127, 0, 127);                           \
        fa  = ld32(smem[B][2], wm + lrow, khalf);                             \
        fb0 = ld32(smem[B][3], wn + lrow, khalf);                             \
        fb1 = ld32(smem[B][3], wn + 32 + lrow, khalf);                        \
        acc_t0 = __builtin_amdgcn_mfma_scale_f32_32x32x64_f8f6f4(             \
            fa, fb0, acc_t0, 0, 0, 0, 127, 0, 127);                           \
        acc_t1 = __builtin_amdgcn_mfma_scale_f32_32x32x64_f8f6f4(             \
            fa, fb1, acc_t1, 0, 0, 0, 127, 0, 127);                           \
    }

// Counted vmcnt (T4): next step's 4 loads stay in flight across the barrier.
#define STEP_MX(KT, B)                                                        \
    {                                                                         \
        if ((KT) + 1 < NKTM) {                                                \
            STAGE_MX((KT) + 1, (B) ^ 1);                                      \
            asm volatile("s_waitcnt vmcnt(4)" ::: "memory");                  \
        } else {                                                              \
            asm volatile("s_waitcnt vmcnt(0)" ::: "memory");                  \
        }                                                                     \
        __builtin_amdgcn_sched_barrier(0);                                    \
        __builtin_amdgcn_s_barrier();                                         \
        COMPUTE_MX(B);                                                        \
        __builtin_amdgcn_s_barrier();                                         \
    }

// ---------------------------------------------------------------------------
// Strip GEMM (MX fp8 32x32x64, 8 waves): wave grid 4Mx2N, per-wave 32x64 tile
// -> 64 acc f32/thread (no spill). Per-g non-atomic partials writes.
// ---------------------------------------------------------------------------
__global__ __launch_bounds__(512, 4) void fused_gemm_mx(
    const unsigned char* __restrict__ blob,
    const int* __restrict__ labels, float* __restrict__ partials)
{
    __shared__ __align__(16) unsigned char smem[2][4][BLOBM];   // 64 KB
    __shared__ int lbl[BM];
    const unsigned char* sinb = blob;
    const unsigned char* tinb = blob + INB_B;
    const unsigned char* swb  = blob + 2 * INB_B;
    const unsigned char* twb  = blob + 2 * INB_B + WB_B;

    const int tid = threadIdx.x;
    const int orig = blockIdx.x;
    const int swzb = (orig & 7) * (NSTRIP / 8) + (orig >> 3);   // XCD-bijective
    const int vbg = swzb >> 4, rb = swzb & 15;
    const int row0 = rb * BM;
    if (tid < BM) lbl[tid] = labels[row0 + tid];

    const int lane = tid & 63, wave = tid >> 6;
    const int wm = (wave >> 1) * 32;      // 4 M-strips of 32
    const int wn = (wave & 1) * 64;       // 2 N-strips of 64
    const int lrow = lane & 31, khalf = lane >> 5;

    const unsigned char* g0 = sinb + (size_t)(rb * NKTM) * BLOBM;
    const unsigned char* g2 = tinb + (size_t)(rb * NKTM) * BLOBM;

    for (int g = 0; g < VBG; ++g) {
        const int vb = vbg * VBG + g;
        const int n0 = vb * BN;
        const unsigned char* g1 = swb + (size_t)(vb * NKTM) * BLOBM;
        const unsigned char* g3 = twb + (size_t)(vb * NKTM) * BLOBM;

        f32x16 acc_s0 = {}, acc_s1 = {}, acc_t0 = {}, acc_t1 = {};

        STAGE_MX(0, 0);
#pragma unroll
        for (int kt = 0; kt < NKTM; kt += 2) {
            STEP_MX(kt, 0);
            STEP_MX(kt + 1, 1);
        }

        // C/D (32x32, m74/m101): col = lane&31, row = (reg&3)+8*(reg>>2)+4*(lane>>5)
        const int slot = vb * 2 + (wave & 1);
#pragma unroll
        for (int rg = 0; rg < 16; ++rg) {
            const int rloc = wm + (rg & 3) + 8 * (rg >> 2) + 4 * khalf;
            const int lab = lbl[rloc];
            const float s0 = acc_s0[rg], s1 = acc_s1[rg];
            const float t0 = acc_t0[rg], t1 = acc_t1[rg];
            float es = __expf(s0) + __expf(s1);
            float dt = s0 * t0 + s1 * t1;
            float ss = s0 * s0 + s1 * s1;
            float tt = t0 * t0 + t1 * t1;
            float sl = 0.f;
            if (n0 + wn + lrow == lab)      sl += s0;
            if (n0 + wn + 32 + lrow == lab) sl += s1;
            // reduce over the 32 cols (shfl_xor m<32 stays within lane-half)
#pragma unroll
            for (int m = 1; m < 32; m <<= 1) {
                es += __shfl_xor(es, m, 64);
                dt += __shfl_xor(dt, m, 64);
                ss += __shfl_xor(ss, m, 64);
                tt += __shfl_xor(tt, m, 64);
                sl += __shfl_xor(sl, m, 64);
            }
            if (lrow == 0) {
                const int row = row0 + rloc;
                partials[(size_t)(0 * NSLOT + slot) * BTOK + row] = es;
                partials[(size_t)(1 * NSLOT + slot) * BTOK + row] = dt;
                partials[(size_t)(2 * NSLOT + slot) * BTOK + row] = ss;
                partials[(size_t)(3 * NSLOT + slot) * BTOK + row] = tt;
                partials[(size_t)(4 * NSLOT + slot) * BTOK + row] = sl;
            }
        }
    }
}

// ---------------------------------------------------------------------------
// finalize stage 1: 32 blocks x 64 rows; reduce 500 slots (coalesced).
// ---------------------------------------------------------------------------
__global__ __launch_bounds__(256) void finalize_s1(
    const float* __restrict__ partials, const int* __restrict__ labels,
    float* __restrict__ blocksums)
{
    __shared__ float fsum[4][64][5];
    const int t = threadIdx.x, b = blockIdx.x;
    const int rl = t & 63, w = t >> 6;
    const int row = b * 64 + rl;
    float a0 = 0.f, a1 = 0.f, a2 = 0.f, a3 = 0.f, a4 = 0.f;
    for (int slot = w; slot < NSLOT; slot += 4) {
        const size_t base = (size_t)slot * BTOK + row;
        a0 += partials[(size_t)0 * NSLOT * BTOK + base];
        a1 += partials[(size_t)1 * NSLOT * BTOK + base];
        a2 += partials[(size_t)2 * NSLOT * BTOK + base];
        a3 += partials[(size_t)3 * NSLOT * BTOK + base];
        a4 += partials[(size_t)4 * NSLOT * BTOK + base];
    }
    fsum[w][rl][0] = a0; fsum[w][rl][1] = a1; fsum[w][rl][2] = a2;
    fsum[w][rl][3] = a3; fsum[w][rl][4] = a4;
    __syncthreads();
    if (t < 64) {
        const float es = fsum[0][t][0] + fsum[1][t][0] + fsum[2][t][0] + fsum[3][t][0];
        const float dt = fsum[0][t][1] + fsum[1][t][1] + fsum[2][t][1] + fsum[3][t][1];
        const float ss = fsum[0][t][2] + fsum[1][t][2] + fsum[2][t][2] + fsum[3][t][2];
        const float tt = fsum[0][t][3] + fsum[1][t][3] + fsum[2][t][3] + fsum[3][t][3];
        const float sl = fsum[0][t][4] + fsum[1][t][4] + fsum[2][t][4] + fsum[3][t][4];
        float hard = 0.f, soft;
        if (labels[row] != -100) hard = logf(es) - sl;
        const float ns = fmaxf(sqrtf(ss), 1e-12f);
        const float nt = fmaxf(sqrtf(tt), 1e-12f);
        soft = 1.f - dt / (ns * nt);
#pragma unroll
        for (int m = 1; m < 64; m <<= 1) {
            hard += __shfl_xor(hard, m, 64);
            soft += __shfl_xor(soft, m, 64);
        }
        if (t == 0) {
            blocksums[b * 2 + 0] = hard;
            blocksums[b * 2 + 1] = soft;
        }
    }
}

__global__ void finalize_s2(const float* __restrict__ blocksums,
                            float* __restrict__ out)
{
    const int t = threadIdx.x;   // 64
    float hard = (t < 32) ? blocksums[t * 2 + 0] : 0.f;
    float soft = (t < 32) ? blocksums[t * 2 + 1] : 0.f;
#pragma unroll
    for (int m = 1; m < 64; m <<= 1) {
        hard += __shfl_xor(hard, m, 64);
        soft += __shfl_xor(soft, m, 64);
    }
    if (t == 0)
        out[0] = 0.5f * (hard / (float)BTOK) + 0.25f * (soft / (float)BTOK);
}

// ---------------------------------------------------------------------------
// Fallback (ws too small): R2's validated bf16 fused-conversion kernel.
// ---------------------------------------------------------------------------
#define BKF 32
#define NKTF (HDIM / BKF)
#define TILE_EF (BM * BKF)

__device__ __forceinline__ int swz_e32(int r, int c) {
    return (r * BKF + c) ^ ((r & 7) << 3);
}

__global__ __launch_bounds__(256, 2) void fused_fwd_fb(
    const float* __restrict__ s_in, const float* __restrict__ s_w,
    const float* __restrict__ t_in, const float* __restrict__ t_w,
    const int* __restrict__ labels, float* __restrict__ rowacc)
{
    __shared__ unsigned short smem[2][4][TILE_EF];
    __shared__ int lbl[BM];
    const int tid = threadIdx.x;
    const int orig = blockIdx.x;
    const int swz  = (orig & 7) * (NBLK / 8) + (orig >> 3);
    const int vb = swz >> 4, rb = swz & 15;
    const int n0 = vb * BN, row0 = rb * BM;
    if (tid < BM) lbl[tid] = labels[row0 + tid];
    const int rr = tid >> 3, c8 = tid & 7;
    const float* srcp[4];
    srcp[0] = s_in + (size_t)(row0 + rr) * HDIM + c8 * 4;
    srcp[1] = s_w  + (size_t)(n0   + rr) * HDIM + c8 * 4;
    srcp[2] = t_in + (size_t)(row0 + rr) * HDIM + c8 * 4;
    srcp[3] = t_w  + (size_t)(n0   + rr) * HDIM + c8 * 4;
    f32x4 acc_s[4][4] = {}, acc_t[4][4] = {};
    const int lane = tid & 63, wave = tid >> 6;
    const int wm = (wave >> 1) * 64, wn = (wave & 1) * 64;
    const int lr = lane & 15, lg = lane >> 4;
    const int ec = lg * 8;
    float4 rg[4][4];

#define LOADS_FB(KT)                                                          \
    { const int k0 = (KT) * BKF;                                              \
      _Pragma("unroll") for (int t = 0; t < 4; ++t)                           \
      _Pragma("unroll") for (int it = 0; it < 4; ++it)                        \
          rg[t][it] = *reinterpret_cast<const float4*>(srcp[t] + (size_t)it * 32 * HDIM + k0); }
#define CVT_WRITE_FB(B)                                                       \
    { _Pragma("unroll") for (int t = 0; t < 4; ++t)                           \
      _Pragma("unroll") for (int it = 0; it < 4; ++it) {                      \
          const int r = rr + it * 32;                                         \
          ushort4 h;                                                          \
          h.x = f2b(rg[t][it].x); h.y = f2b(rg[t][it].y);                     \
          h.z = f2b(rg[t][it].z); h.w = f2b(rg[t][it].w);                     \
          *reinterpret_cast<ushort4*>(&smem[B][t][swz_e32(r, c8 * 4)]) = h; } }
#define COMPUTE_FB(B)                                                         \
    { const unsigned short* As = smem[B][0]; const unsigned short* Bs = smem[B][1]; \
      const unsigned short* At = smem[B][2]; const unsigned short* Bt = smem[B][3]; \
      bf16x8 af[4], bfr[4];                                                   \
      _Pragma("unroll") for (int mi = 0; mi < 4; ++mi)                        \
          af[mi] = *reinterpret_cast<const bf16x8*>(As + swz_e32(wm + mi * 16 + lr, ec)); \
      _Pragma("unroll") for (int ni = 0; ni < 4; ++ni)                        \
          bfr[ni] = *reinterpret_cast<const bf16x8*>(Bs + swz_e32(wn + ni * 16 + lr, ec)); \
      _Pragma("unroll") for (int mi = 0; mi < 4; ++mi)                        \
      _Pragma("unroll") for (int ni = 0; ni < 4; ++ni)                        \
          acc_s[mi][ni] = __builtin_amdgcn_mfma_f32_16x16x32_bf16(af[mi], bfr[ni], acc_s[mi][ni], 0, 0, 0); \
      _Pragma("unroll") for (int mi = 0; mi < 4; ++mi)                        \
          af[mi] = *reinterpret_cast<const bf16x8*>(At + swz_e32(wm + mi * 16 + lr, ec)); \
      _Pragma("unroll") for (int ni = 0; ni < 4; ++ni)                        \
          bfr[ni] = *reinterpret_cast<const bf16x8*>(Bt + swz_e32(wn + ni * 16 + lr, ec)); \
      _Pragma("unroll") for (int mi = 0; mi < 4; ++mi)                        \
      _Pragma("unroll") for (int ni = 0; ni < 4; ++ni)                        \
          acc_t[mi][ni] = __builtin_amdgcn_mfma_f32_16x16x32_bf16(af[mi], bfr[ni], acc_t[mi][ni], 0, 0, 0); }

    LOADS_FB(0); CVT_WRITE_FB(0); __syncthreads();
    int cur = 0;
#pragma unroll 2
    for (int kt = 0; kt < NKTF; ++kt) {
        if (kt + 1 < NKTF) LOADS_FB(kt + 1);
        COMPUTE_FB(cur);
        if (kt + 1 < NKTF) CVT_WRITE_FB(cur ^ 1);
        __syncthreads();
        cur ^= 1;
    }
#undef LOADS_FB
#undef CVT_WRITE_FB
#undef COMPUTE_FB
#pragma unroll
    for (int mi = 0; mi < 4; ++mi) {
#pragma unroll
        for (int rg_ = 0; rg_ < 4; ++rg_) {
            const int rloc = wm + mi * 16 + lg * 4 + rg_;
            const int lab = lbl[rloc];
            float es = 0.f, dt = 0.f, ss = 0.f, tt = 0.f, sl = 0.f;
#pragma unroll
            for (int ni = 0; ni < 4; ++ni) {
                const float s = acc_s[mi][ni][rg_];
                const float t = acc_t[mi][ni][rg_];
                es += __expf(s); dt += s * t; ss += s * s; tt += t * t;
                if (n0 + wn + ni * 16 + lr == lab) sl += s;
            }
#pragma unroll
            for (int m = 1; m < 16; m <<= 1) {
                es += __shfl_xor(es, m, 64); dt += __shfl_xor(dt, m, 64);
                ss += __shfl_xor(ss, m, 64); tt += __shfl_xor(tt, m, 64);
                sl += __shfl_xor(sl, m, 64);
            }
            if (lr == 0) {
                float* ra = rowacc + (size_t)(row0 + rloc) * 5;
                atomicAdd(ra + 0, es); atomicAdd(ra + 1, dt); atomicAdd(ra + 2, ss);
                atomicAdd(ra + 3, tt); atomicAdd(ra + 4, sl);
            }
        }
    }
}

__global__ __launch_bounds__(256) void finalize(const float* __restrict__ rowacc,
                                                const int* __restrict__ labels,
                                                float* __restrict__ out)
{
    const int tid = threadIdx.x;
    float hard = 0.f, soft = 0.f;
    for (int r = tid; r < BTOK; r += 256) {
        const float* ra = rowacc + (size_t)r * 5;
        const float es = ra[0], dt = ra[1], ss = ra[2], tt = ra[3], sl = ra[4];
        if (labels[r] != -100) hard += logf(es) - sl;
        const float ns = fmaxf(sqrtf(ss), 1e-12f);
        const float nt = fmaxf(sqrtf(tt), 1e-12f);
        soft += 1.f - dt / (ns * nt);
    }
#pragma unroll
    for (int m = 1; m < 64; m <<= 1) {
        hard += __shfl_xor(hard, m, 64);
        soft += __shfl_xor(soft, m, 64);
    }
    __shared__ float sh[2][4];
    const int w = tid >> 6;
    if ((tid & 63) == 0) { sh[0][w] = hard; sh[1][w] = soft; }
    __syncthreads();
    if (tid == 0) {
        const float h = sh[0][0] + sh[0][1] + sh[0][2] + sh[0][3];
        const float s = sh[1][0] + sh[1][1] + sh[1][2] + sh[1][3];
        out[0] = 0.5f * (h / (float)BTOK) + 0.5f * (0.5f * s / (float)BTOK);
    }
}

extern "C" void kernel_launch(void* const* d_in, const int* in_sizes, int n_in,
                              void* d_out, int out_size, void* d_ws, size_t ws_size,
                              hipStream_t stream)
{
    const float* s_in   = (const float*)d_in[0];
    const float* s_w    = (const float*)d_in[1];
    const float* t_in   = (const float*)d_in[2];
    const float* t_w    = (const float*)d_in[3];
    const int*   labels = (const int*)d_in[4];

    if (ws_size >= WS_NEED) {
        unsigned char* blob = (unsigned char*)d_ws + WS_BLOB_OFF;
        float* partials  = (float*)((char*)d_ws + PART_OFF);
        float* blocksums = (float*)d_ws;
        convert_pack_mx<<<2048, 256, 0, stream>>>(s_in, s_w, t_in, t_w, blob);
        fused_gemm_mx<<<NSTRIP, 512, 0, stream>>>(blob, labels, partials);
        finalize_s1<<<BTOK / 64, 256, 0, stream>>>(partials, labels, blocksums);
        finalize_s2<<<1, 64, 0, stream>>>(blocksums, (float*)d_out);
    } else {
        float* rowacc = (float*)d_ws;
        hipMemsetAsync(rowacc, 0, (size_t)BTOK * 5 * sizeof(float), stream);
        fused_fwd_fb<<<NBLK, 256, 0, stream>>>(s_in, s_w, t_in, t_w, labels, rowacc);
        finalize<<<1, 256, 0, stream>>>(rowacc, labels, (float*)d_out);
    }
}

// Round 10
// 195.147 us; speedup vs baseline: 3.3818x; 1.6948x over previous
//
#include <hip/hip_runtime.h>
#include <stdint.h>

#define BTOK 2048
#define HDIM 512
#define VOC  32000
#define BM 128
#define BN 128
#define BKM 64                   // K per step (MX 32x32x64)
#define NKTM (HDIM / BKM)        // 8 K-steps
#define BLOBM (BM * BKM)         // 8192 B per (panel, kt) blob (fp8)
#define NVB (VOC / BN)           // 250
#define NRB (BTOK / BM)          // 16
#define NBLK (NVB * NRB)         // 4000 (fallback grid)
#define VBG 5                    // vocab blocks per strip
#define NVBG (NVB / VBG)         // 50
#define NSTRIP (NVBG * NRB)      // 800 (% 8 == 0)
#define NSLOT (NVBG * 2)         // 100 partial slots (vbg x wave-n-half)

// ws layout:
//   [0, 256)        blocksums
//   [65536, ..)     fp8 blobs: s_in | t_in | s_w | t_w
//   [PART_OFF, ..)  partials[5][NSLOT][BTOK] f32
#define WS_BLOB_OFF 65536
#define INB_B ((size_t)BTOK * HDIM)
#define WB_B  ((size_t)VOC * HDIM)
#define BLOB_BYTES (2 * INB_B + 2 * WB_B)          // 34,865,152
#define PART_OFF (WS_BLOB_OFF + BLOB_BYTES)
#define PART_BYTES ((size_t)5 * NSLOT * BTOK * 4)  // 4,096,000
#define WS_NEED (PART_OFF + PART_BYTES)            // ~39 MB

typedef __attribute__((ext_vector_type(8)))  short bf16x8;
typedef __attribute__((ext_vector_type(4)))  float f32x4;
typedef __attribute__((ext_vector_type(16))) float f32x16;
typedef __attribute__((ext_vector_type(8)))  int   i32x8;

__device__ __forceinline__ unsigned short f2b(float f) {
    union { float f; uint32_t u; } x; x.f = f;
    uint32_t u = x.u;
    u += 0x7fffu + ((u >> 16) & 1u);   // RNE (fallback path)
    return (unsigned short)(u >> 16);
}

// ---------------------------------------------------------------------------
// Pass 1: f32 -> fp8 e4m3 blobs, 64B rows, full-address XOR swizzle:
//   e = (r*64 + cc) ^ ((r&7)<<4)
// (bits 4-5 permute 16B granules; bit 6 flips row LSB - bijective, R5 rule.)
// Read side applies the SAME involution.
// ---------------------------------------------------------------------------
__global__ __launch_bounds__(256) void convert_pack_mx(
    const float* __restrict__ s_in, const float* __restrict__ s_w,
    const float* __restrict__ t_in, const float* __restrict__ t_w,
    unsigned char* __restrict__ blob)
{
    unsigned char* sinb = blob;
    unsigned char* tinb = blob + INB_B;
    unsigned char* swb  = blob + 2 * INB_B;
    unsigned char* twb  = blob + 2 * INB_B + WB_B;
    const int total8 = (2 * BTOK + 2 * VOC) * (HDIM / 8);
    for (int f = blockIdx.x * 256 + threadIdx.x; f < total8; f += gridDim.x * 256) {
        const int row = f >> 6;
        const int c8i = f & 63;
        const float* src; unsigned char* dstb; int lrow;
        if (row < BTOK)                { src = s_in; dstb = sinb; lrow = row; }
        else if (row < BTOK + VOC)     { src = s_w;  dstb = swb;  lrow = row - BTOK; }
        else if (row < 2*BTOK + VOC)   { src = t_in; dstb = tinb; lrow = row - (BTOK + VOC); }
        else                           { src = t_w;  dstb = twb;  lrow = row - (2*BTOK + VOC); }
        const float* sp = src + (size_t)lrow * HDIM + c8i * 8;
        const float4 v0 = *reinterpret_cast<const float4*>(sp);
        const float4 v1 = *reinterpret_cast<const float4*>(sp + 4);
        const int p = lrow >> 7, r = lrow & 127;
        const int ccf = c8i * 8, kt = ccf >> 6, cc = ccf & 63;
        const int e = (r * BKM + cc) ^ ((r & 7) << 4);
        uint32_t w0 = 0, w1 = 0;
        w0 = __builtin_amdgcn_cvt_pk_fp8_f32(v0.x, v0.y, w0, false);
        w0 = __builtin_amdgcn_cvt_pk_fp8_f32(v0.z, v0.w, w0, true);
        w1 = __builtin_amdgcn_cvt_pk_fp8_f32(v1.x, v1.y, w1, false);
        w1 = __builtin_amdgcn_cvt_pk_fp8_f32(v1.z, v1.w, w1, true);
        uint2 pk; pk.x = w0; pk.y = w1;
        *reinterpret_cast<uint2*>(dstb + (size_t)(p * NKTM + kt) * BLOBM + e) = pk;
    }
}

__device__ __forceinline__ void gl_lds16(const unsigned char* g, unsigned char* l) {
    __builtin_amdgcn_global_load_lds(
        (__attribute__((address_space(1))) const void*)g,
        (__attribute__((address_space(3))) void*)l, 16, 0, 0);
}

// Read one 32B MFMA operand from a swizzled 128x64 panel.
__device__ __forceinline__ i32x8 ld32(const unsigned char* base, int row, int khalf) {
    const int swz = (row & 7) << 4;
    const int a0 = (row * BKM + khalf * 32) ^ swz;
    const int a1 = (row * BKM + khalf * 32 + 16) ^ swz;
    const int4 lo = *reinterpret_cast<const int4*>(base + a0);
    const int4 hi = *reinterpret_cast<const int4*>(base + a1);
    i32x8 v;
    v[0] = lo.x; v[1] = lo.y; v[2] = lo.z; v[3] = lo.w;
    v[4] = hi.x; v[5] = hi.y; v[6] = hi.z; v[7] = hi.w;
    return v;
}

// A+B staging (g=0 pass): 4 loads/thread. 512 thr x 16B = full 8KB panel each.
#define STAGE_AB(KT, B, PB1, PB3)                                             \
    {                                                                         \
        const size_t kb = (size_t)(KT) * BLOBM;                               \
        const int off = tid * 16;                                             \
        gl_lds16(g0 + kb + off, &smem[B][0][off]);                            \
        gl_lds16((PB1) + kb + off, &smem[B][1][off]);                         \
        gl_lds16(g2 + kb + off, &smem[B][2][off]);                            \
        gl_lds16((PB3) + kb + off, &smem[B][3][off]);                         \
    }

// B-only staging (g>=1: A panels already resident, parity-aligned): 2 loads.
#define STAGE_B2(KT, B, PB1, PB3)                                             \
    {                                                                         \
        const size_t kb = (size_t)(KT) * BLOBM;                               \
        const int off = tid * 16;                                             \
        gl_lds16((PB1) + kb + off, &smem[B][1][off]);                         \
        gl_lds16((PB3) + kb + off, &smem[B][3][off]);                         \
    }

// Per wave: 1 A-frag + 2 B-frags per matrix, 4 mfma_scale (scale=1.0: E8M0 127).
#define COMPUTE_MX(B)                                                         \
    {                                                                         \
        i32x8 fa, fb0, fb1;                                                   \
        fa  = ld32(smem[B][0], wm + lrow, khalf);                             \
        fb0 = ld32(smem[B][1], wn + lrow, khalf);                             \
        fb1 = ld32(smem[B][1], wn + 32 + lrow, khalf);                        \
        acc_s0 = __builtin_amdgcn_mfma_scale_f32_32x32x64_f8f6f4(             \
            fa, fb0, acc_s0, 0, 0, 0, 127, 0, 127);                           \
        acc_s1 = __builtin_amdgcn_mfma_scale_f32_32x32x64_f8f6f4(             \
            fa, fb1, acc_s1, 0, 0, 0, 127, 0, 127);                           \
        fa  = ld32(smem[B][2], wm + lrow, khalf);                             \
        fb0 = ld32(smem[B][3], wn + lrow, khalf);                             \
        fb1 = ld32(smem[B][3], wn + 32 + lrow, khalf);                        \
        acc_t0 = __builtin_amdgcn_mfma_scale_f32_32x32x64_f8f6f4(             \
            fa, fb0, acc_t0, 0, 0, 0, 127, 0, 127);                           \
        acc_t1 = __builtin_amdgcn_mfma_scale_f32_32x32x64_f8f6f4(             \
            fa, fb1, acc_t1, 0, 0, 0, 127, 0, 127);                          \
    }

// Counted vmcnt (T4): VM = loads issued after the ones we must wait for.
// Never drains to 0 except the very last step of the last g.
#define CORE(B, VM)                                                           \
    {                                                                         \
        asm volatile("s_waitcnt vmcnt(" #VM ")" ::: "memory");                \
        __builtin_amdgcn_sched_barrier(0);                                    \
        __builtin_amdgcn_s_barrier();                                         \
        COMPUTE_MX(B);                                                        \
        __builtin_amdgcn_s_barrier();                                         \
    }

// ---------------------------------------------------------------------------
// Strip GEMM (MX fp8 32x32x64, 8 waves, VBG=5): A panels staged once per
// block (g=0) and reused across all 5 vocab blocks (buffer parity aligned:
// 8 even steps -> As/At(kt) always in buf[kt&1]). Loss partials accumulate
// in registers across the strip; ONE shuffle-reduce + write per block.
// ---------------------------------------------------------------------------
__global__ __launch_bounds__(512, 2) void fused_gemm_mx(
    const unsigned char* __restrict__ blob,
    const int* __restrict__ labels, float* __restrict__ partials)
{
    __shared__ __align__(16) unsigned char smem[2][4][BLOBM];   // 64 KB
    __shared__ int lbl[BM];
    const unsigned char* sinb = blob;
    const unsigned char* tinb = blob + INB_B;
    const unsigned char* swb  = blob + 2 * INB_B;
    const unsigned char* twb  = blob + 2 * INB_B + WB_B;

    const int tid = threadIdx.x;
    const int orig = blockIdx.x;
    const int swzb = (orig & 7) * (NSTRIP / 8) + (orig >> 3);   // XCD-bijective
    const int vbg = swzb >> 4, rb = swzb & 15;
    const int row0 = rb * BM;
    if (tid < BM) lbl[tid] = labels[row0 + tid];
    __syncthreads();

    const int lane = tid & 63, wave = tid >> 6;
    const int wm = (wave >> 1) * 32;      // 4 M-strips of 32
    const int wn = (wave & 1) * 64;       // 2 N-strips of 64
    const int lrow = lane & 31, khalf = lane >> 5;

    const unsigned char* g0 = sinb + (size_t)(rb * NKTM) * BLOBM;
    const unsigned char* g2 = tinb + (size_t)(rb * NKTM) * BLOBM;
    const unsigned char* pb1 = swb + (size_t)(vbg * VBG * NKTM) * BLOBM;
    const unsigned char* pb3 = twb + (size_t)(vbg * VBG * NKTM) * BLOBM;

    // labels for this thread's 16 output rows, hoisted to registers
    int labr[16];
#pragma unroll
    for (int rg = 0; rg < 16; ++rg)
        labr[rg] = lbl[wm + (rg & 3) + 8 * (rg >> 2) + 4 * khalf];

    // strip-accumulated loss partials (80 VGPRs, statically indexed)
    float pes[16], pdt[16], pss[16], ptt[16], psl[16];
#pragma unroll
    for (int i = 0; i < 16; ++i) {
        pes[i] = 0.f; pdt[i] = 0.f; pss[i] = 0.f; ptt[i] = 0.f; psl[i] = 0.f;
    }

    STAGE_AB(0, 0, pb1, pb3);
    for (int g = 0; g < VBG; ++g) {
        const int n0 = (vbg * VBG + g) * BN;
        f32x16 acc_s0 = {}, acc_s1 = {}, acc_t0 = {}, acc_t1 = {};

        if (g == 0) {
            // first pass: stage A+B each step (4 loads -> vmcnt(4))
#pragma unroll
            for (int kt = 0; kt < NKTM - 1; ++kt) {
                STAGE_AB(kt + 1, (kt + 1) & 1, pb1, pb3);
                CORE(kt & 1, 4);
            }
            STAGE_B2(NKTM, 0, pb1, pb3);    // next g's B(0) into buf0
            CORE(1, 2);
        } else if (g < VBG - 1) {
#pragma unroll
            for (int kt = 0; kt < NKTM - 1; ++kt) {
                STAGE_B2(kt + 1, (kt + 1) & 1, pb1, pb3);
                CORE(kt & 1, 2);
            }
            STAGE_B2(NKTM, 0, pb1, pb3);
            CORE(1, 2);
        } else {
#pragma unroll
            for (int kt = 0; kt < NKTM - 1; ++kt) {
                STAGE_B2(kt + 1, (kt + 1) & 1, pb1, pb3);
                CORE(kt & 1, 2);
            }
            CORE(1, 0);                     // only full drain in the kernel
        }
        pb1 += (size_t)NKTM * BLOBM;
        pb3 += (size_t)NKTM * BLOBM;

        // element-wise accumulate into register partials
        // C/D (32x32): col = lane&31, row = (reg&3)+8*(reg>>2)+4*(lane>>5)
#pragma unroll
        for (int rg = 0; rg < 16; ++rg) {
            const float s0 = acc_s0[rg], s1 = acc_s1[rg];
            const float t0 = acc_t0[rg], t1 = acc_t1[rg];
            pes[rg] += __expf(s0) + __expf(s1);
            pdt[rg] += s0 * t0 + s1 * t1;
            pss[rg] += s0 * s0 + s1 * s1;
            ptt[rg] += t0 * t0 + t1 * t1;
            const int lab = labr[rg];
            if (n0 + wn + lrow == lab)      psl[rg] += s0;
            if (n0 + wn + 32 + lrow == lab) psl[rg] += s1;
        }
    }

    // one shuffle-reduce + one non-atomic write per rg for the whole strip
    const int slot = vbg * 2 + (wave & 1);
#pragma unroll
    for (int rg = 0; rg < 16; ++rg) {
        float es = pes[rg], dt = pdt[rg], ss = pss[rg], tt = ptt[rg], sl = psl[rg];
#pragma unroll
        for (int m = 1; m < 32; m <<= 1) {
            es += __shfl_xor(es, m, 64);
            dt += __shfl_xor(dt, m, 64);
            ss += __shfl_xor(ss, m, 64);
            tt += __shfl_xor(tt, m, 64);
            sl += __shfl_xor(sl, m, 64);
        }
        if (lrow == 0) {
            const int row = row0 + wm + (rg & 3) + 8 * (rg >> 2) + 4 * khalf;
            partials[(size_t)(0 * NSLOT + slot) * BTOK + row] = es;
            partials[(size_t)(1 * NSLOT + slot) * BTOK + row] = dt;
            partials[(size_t)(2 * NSLOT + slot) * BTOK + row] = ss;
            partials[(size_t)(3 * NSLOT + slot) * BTOK + row] = tt;
            partials[(size_t)(4 * NSLOT + slot) * BTOK + row] = sl;
        }
    }
}

// ---------------------------------------------------------------------------
// finalize stage 1: 32 blocks x 64 rows; reduce 100 slots (coalesced).
// ---------------------------------------------------------------------------
__global__ __launch_bounds__(256) void finalize_s1(
    const float* __restrict__ partials, const int* __restrict__ labels,
    float* __restrict__ blocksums)
{
    __shared__ float fsum[4][64][5];
    const int t = threadIdx.x, b = blockIdx.x;
    const int rl = t & 63, w = t >> 6;
    const int row = b * 64 + rl;
    float a0 = 0.f, a1 = 0.f, a2 = 0.f, a3 = 0.f, a4 = 0.f;
    for (int slot = w; slot < NSLOT; slot += 4) {
        const size_t base = (size_t)slot * BTOK + row;
        a0 += partials[(size_t)0 * NSLOT * BTOK + base];
        a1 += partials[(size_t)1 * NSLOT * BTOK + base];
        a2 += partials[(size_t)2 * NSLOT * BTOK + base];
        a3 += partials[(size_t)3 * NSLOT * BTOK + base];
        a4 += partials[(size_t)4 * NSLOT * BTOK + base];
    }
    fsum[w][rl][0] = a0; fsum[w][rl][1] = a1; fsum[w][rl][2] = a2;
    fsum[w][rl][3] = a3; fsum[w][rl][4] = a4;
    __syncthreads();
    if (t < 64) {
        const float es = fsum[0][t][0] + fsum[1][t][0] + fsum[2][t][0] + fsum[3][t][0];
        const float dt = fsum[0][t][1] + fsum[1][t][1] + fsum[2][t][1] + fsum[3][t][1];
        const float ss = fsum[0][t][2] + fsum[1][t][2] + fsum[2][t][2] + fsum[3][t][2];
        const float tt = fsum[0][t][3] + fsum[1][t][3] + fsum[2][t][3] + fsum[3][t][3];
        const float sl = fsum[0][t][4] + fsum[1][t][4] + fsum[2][t][4] + fsum[3][t][4];
        float hard = 0.f, soft;
        if (labels[row] != -100) hard = logf(es) - sl;
        const float ns = fmaxf(sqrtf(ss), 1e-12f);
        const float nt = fmaxf(sqrtf(tt), 1e-12f);
        soft = 1.f - dt / (ns * nt);
#pragma unroll
        for (int m = 1; m < 64; m <<= 1) {
            hard += __shfl_xor(hard, m, 64);
            soft += __shfl_xor(soft, m, 64);
        }
        if (t == 0) {
            blocksums[b * 2 + 0] = hard;
            blocksums[b * 2 + 1] = soft;
        }
    }
}

__global__ void finalize_s2(const float* __restrict__ blocksums,
                            float* __restrict__ out)
{
    const int t = threadIdx.x;   // 64
    float hard = (t < 32) ? blocksums[t * 2 + 0] : 0.f;
    float soft = (t < 32) ? blocksums[t * 2 + 1] : 0.f;
#pragma unroll
    for (int m = 1; m < 64; m <<= 1) {
        hard += __shfl_xor(hard, m, 64);
        soft += __shfl_xor(soft, m, 64);
    }
    if (t == 0)
        out[0] = 0.5f * (hard / (float)BTOK) + 0.25f * (soft / (float)BTOK);
}

// ---------------------------------------------------------------------------
// Fallback (ws too small): R2's validated bf16 fused-conversion kernel.
// ---------------------------------------------------------------------------
#define BKF 32
#define NKTF (HDIM / BKF)
#define TILE_EF (BM * BKF)

__device__ __forceinline__ int swz_e32(int r, int c) {
    return (r * BKF + c) ^ ((r & 7) << 3);
}

__global__ __launch_bounds__(256, 2) void fused_fwd_fb(
    const float* __restrict__ s_in, const float* __restrict__ s_w,
    const float* __restrict__ t_in, const float* __restrict__ t_w,
    const int* __restrict__ labels, float* __restrict__ rowacc)
{
    __shared__ unsigned short smem[2][4][TILE_EF];
    __shared__ int lbl[BM];
    const int tid = threadIdx.x;
    const int orig = blockIdx.x;
    const int swz  = (orig & 7) * (NBLK / 8) + (orig >> 3);
    const int vb = swz >> 4, rb = swz & 15;
    const int n0 = vb * BN, row0 = rb * BM;
    if (tid < BM) lbl[tid] = labels[row0 + tid];
    const int rr = tid >> 3, c8 = tid & 7;
    const float* srcp[4];
    srcp[0] = s_in + (size_t)(row0 + rr) * HDIM + c8 * 4;
    srcp[1] = s_w  + (size_t)(n0   + rr) * HDIM + c8 * 4;
    srcp[2] = t_in + (size_t)(row0 + rr) * HDIM + c8 * 4;
    srcp[3] = t_w  + (size_t)(n0   + rr) * HDIM + c8 * 4;
    f32x4 acc_s[4][4] = {}, acc_t[4][4] = {};
    const int lane = tid & 63, wave = tid >> 6;
    const int wm = (wave >> 1) * 64, wn = (wave & 1) * 64;
    const int lr = lane & 15, lg = lane >> 4;
    const int ec = lg * 8;
    float4 rg[4][4];

#define LOADS_FB(KT)                                                          \
    { const int k0 = (KT) * BKF;                                              \
      _Pragma("unroll") for (int t = 0; t < 4; ++t)                           \
      _Pragma("unroll") for (int it = 0; it < 4; ++it)                        \
          rg[t][it] = *reinterpret_cast<const float4*>(srcp[t] + (size_t)it * 32 * HDIM + k0); }
#define CVT_WRITE_FB(B)                                                       \
    { _Pragma("unroll") for (int t = 0; t < 4; ++t)                           \
      _Pragma("unroll") for (int it = 0; it < 4; ++it) {                      \
          const int r = rr + it * 32;                                         \
          ushort4 h;                                                          \
          h.x = f2b(rg[t][it].x); h.y = f2b(rg[t][it].y);                     \
          h.z = f2b(rg[t][it].z); h.w = f2b(rg[t][it].w);                     \
          *reinterpret_cast<ushort4*>(&smem[B][t][swz_e32(r, c8 * 4)]) = h; } }
#define COMPUTE_FB(B)                                                         \
    { const unsigned short* As = smem[B][0]; const unsigned short* Bs = smem[B][1]; \
      const unsigned short* At = smem[B][2]; const unsigned short* Bt = smem[B][3]; \
      bf16x8 af[4], bfr[4];                                                   \
      _Pragma("unroll") for (int mi = 0; mi < 4; ++mi)                        \
          af[mi] = *reinterpret_cast<const bf16x8*>(As + swz_e32(wm + mi * 16 + lr, ec)); \
      _Pragma("unroll") for (int ni = 0; ni < 4; ++ni)                        \
          bfr[ni] = *reinterpret_cast<const bf16x8*>(Bs + swz_e32(wn + ni * 16 + lr, ec)); \
      _Pragma("unroll") for (int mi = 0; mi < 4; ++mi)                        \
      _Pragma("unroll") for (int ni = 0; ni < 4; ++ni)                        \
          acc_s[mi][ni] = __builtin_amdgcn_mfma_f32_16x16x32_bf16(af[mi], bfr[ni], acc_s[mi][ni], 0, 0, 0); \
      _Pragma("unroll") for (int mi = 0; mi < 4; ++mi)                        \
          af[mi] = *reinterpret_cast<const bf16x8*>(At + swz_e32(wm + mi * 16 + lr, ec)); \
      _Pragma("unroll") for (int ni = 0; ni < 4; ++ni)                        \
          bfr[ni] = *reinterpret_cast<const bf16x8*>(Bt + swz_e32(wn + ni * 16 + lr, ec)); \
      _Pragma("unroll") for (int mi = 0; mi < 4; ++mi)                        \
      _Pragma("unroll") for (int ni = 0; ni < 4; ++ni)                        \
          acc_t[mi][ni] = __builtin_amdgcn_mfma_f32_16x16x32_bf16(af[mi], bfr[ni], acc_t[mi][ni], 0, 0, 0); }

    LOADS_FB(0); CVT_WRITE_FB(0); __syncthreads();
    int cur = 0;
#pragma unroll 2
    for (int kt = 0; kt < NKTF; ++kt) {
        if (kt + 1 < NKTF) LOADS_FB(kt + 1);
        COMPUTE_FB(cur);
        if (kt + 1 < NKTF) CVT_WRITE_FB(cur ^ 1);
        __syncthreads();
        cur ^= 1;
    }
#undef LOADS_FB
#undef CVT_WRITE_FB
#undef COMPUTE_FB
#pragma unroll
    for (int mi = 0; mi < 4; ++mi) {
#pragma unroll
        for (int rg_ = 0; rg_ < 4; ++rg_) {
            const int rloc = wm + mi * 16 + lg * 4 + rg_;
            const int lab = lbl[rloc];
            float es = 0.f, dt = 0.f, ss = 0.f, tt = 0.f, sl = 0.f;
#pragma unroll
            for (int ni = 0; ni < 4; ++ni) {
                const float s = acc_s[mi][ni][rg_];
                const float t = acc_t[mi][ni][rg_];
                es += __expf(s); dt += s * t; ss += s * s; tt += t * t;
                if (n0 + wn + ni * 16 + lr == lab) sl += s;
            }
#pragma unroll
            for (int m = 1; m < 16; m <<= 1) {
                es += __shfl_xor(es, m, 64); dt += __shfl_xor(dt, m, 64);
                ss += __shfl_xor(ss, m, 64); tt += __shfl_xor(tt, m, 64);
                sl += __shfl_xor(sl, m, 64);
            }
            if (lr == 0) {
                float* ra = rowacc + (size_t)(row0 + rloc) * 5;
                atomicAdd(ra + 0, es); atomicAdd(ra + 1, dt); atomicAdd(ra + 2, ss);
                atomicAdd(ra + 3, tt); atomicAdd(ra + 4, sl);
            }
        }
    }
}

__global__ __launch_bounds__(256) void finalize(const float* __restrict__ rowacc,
                                                const int* __restrict__ labels,
                                                float* __restrict__ out)
{
    const int tid = threadIdx.x;
    float hard = 0.f, soft = 0.f;
    for (int r = tid; r < BTOK; r += 256) {
        const float* ra = rowacc + (size_t)r * 5;
        const float es = ra[0], dt = ra[1], ss = ra[2], tt = ra[3], sl = ra[4];
        if (labels[r] != -100) hard += logf(es) - sl;
        const float ns = fmaxf(sqrtf(ss), 1e-12f);
        const float nt = fmaxf(sqrtf(tt), 1e-12f);
        soft += 1.f - dt / (ns * nt);
    }
#pragma unroll
    for (int m = 1; m < 64; m <<= 1) {
        hard += __shfl_xor(hard, m, 64);
        soft += __shfl_xor(soft, m, 64);
    }
    __shared__ float sh[2][4];
    const int w = tid >> 6;
    if ((tid & 63) == 0) { sh[0][w] = hard; sh[1][w] = soft; }
    __syncthreads();
    if (tid == 0) {
        const float h = sh[0][0] + sh[0][1] + sh[0][2] + sh[0][3];
        const float s = sh[1][0] + sh[1][1] + sh[1][2] + sh[1][3];
        out[0] = 0.5f * (h / (float)BTOK) + 0.5f * (0.5f * s / (float)BTOK);
    }
}

extern "C" void kernel_launch(void* const* d_in, const int* in_sizes, int n_in,
                              void* d_out, int out_size, void* d_ws, size_t ws_size,
                              hipStream_t stream)
{
    const float* s_in   = (const float*)d_in[0];
    const float* s_w    = (const float*)d_in[1];
    const float* t_in   = (const float*)d_in[2];
    const float* t_w    = (const float*)d_in[3];
    const int*   labels = (const int*)d_in[4];

    if (ws_size >= WS_NEED) {
        unsigned char* blob = (unsigned char*)d_ws + WS_BLOB_OFF;
        float* partials  = (float*)((char*)d_ws + PART_OFF);
        float* blocksums = (float*)d_ws;
        convert_pack_mx<<<2048, 256, 0, stream>>>(s_in, s_w, t_in, t_w, blob);
        fused_gemm_mx<<<NSTRIP, 512, 0, stream>>>(blob, labels, partials);
        finalize_s1<<<BTOK / 64, 256, 0, stream>>>(partials, labels, blocksums);
        finalize_s2<<<1, 64, 0, stream>>>(blocksums, (float*)d_out);
    } else {
        float* rowacc = (float*)d_ws;
        hipMemsetAsync(rowacc, 0, (size_t)BTOK * 5 * sizeof(float), stream);
        fused_fwd_fb<<<NBLK, 256, 0, stream>>>(s_in, s_w, t_in, t_w, labels, rowacc);
        finalize<<<1, 256, 0, stream>>>(rowacc, labels, (float*)d_out);
    }
}